// Round 9
// baseline (978.936 us; speedup 1.0000x reference)
//
#include <hip/hip_runtime.h>
#include <hip/hip_bf16.h>
#include <hip/hip_cooperative_groups.h>

namespace cg = cooperative_groups;
using bf16 = __hip_bfloat16;
typedef __attribute__((ext_vector_type(8))) short short8;
typedef __attribute__((ext_vector_type(4))) float f32x4;

constexpr int N   = 50000;
constexpr int E   = 800000;
constexpr int NIN = 300;
constexpr int H   = 4;
constexpr int C   = 64;
constexpr int HC  = H * C;      // 256
constexpr int G   = 256;
constexpr int NOUT = 768;
constexpr int NKB = 10;         // K blocks of 32 (K padded 300->320)
constexpr int MP  = 50048;      // M padded to 782*64
constexpr int XSP = 328;        // LDS row pitch (bf16 elems)
constexpr int NCH = (N + 255) / 256;   // 196 scan chunks

__device__ __forceinline__ float b2f(bf16 v) { return __bfloat162float(v); }
__device__ __forceinline__ float us2f(unsigned short u) {
    bf16 b; *(unsigned short*)&b = u; return __bfloat162float(b);
}
__device__ __forceinline__ unsigned short f2us(float f) {
    bf16 b = __float2bfloat16(f); return *(unsigned short*)&b;
}
__device__ __forceinline__ float lrelu_att(float v) { return v > 0.f ? v : 0.2f * v; }
__device__ __forceinline__ float lrelu_act(float v) { return v > 0.f ? v : 0.01f * v; }
__device__ __forceinline__ float ldin(const void* p, int isbf, size_t i) {
    return isbf ? b2f(((const bf16*)p)[i]) : ((const float*)p)[i];
}

// in-block dtype detection (reads first 256 uint16s of x; deterministic)
__device__ __forceinline__ int block_detect(const unsigned short* __restrict__ xr) {
    __shared__ int cnt_s;
    if (threadIdx.x == 0) cnt_s = 0;
    __syncthreads();
    unsigned short u = xr[threadIdx.x & 255];
    int ex = (u >> 7) & 0xFF;
    int ok = (ex == 0) || (ex >= 100 && ex <= 140);
    if (threadIdx.x < 256) atomicAdd(&cnt_s, ok);
    __syncthreads();
    return (cnt_s >= 240) ? 1 : 0;   // 1 = bf16 inputs
}

// ---------------- pre: detect->flag | swizzle w | graph ranges ----------------
__global__ __launch_bounds__(256) void k_pre(const unsigned short* __restrict__ xr,
                                             const void* __restrict__ w,
                                             const int* __restrict__ batch,
                                             int* __restrict__ flag,
                                             unsigned short* __restrict__ bswz,
                                             int* __restrict__ gs) {
    int b = blockIdx.x;
    if (b < 40) {
        int isbf = block_detect(xr);
        if (b == 0 && threadIdx.x == 0) *flag = isbf;
        int fb = b * 4 + (threadIdx.x >> 6);   // kb*16+nb, 0..159
        if (fb < 160) {
            int kb = fb >> 4, nb = fb & 15;
            int lane = threadIdx.x & 63;
            int q = lane >> 4, cl = lane & 15;
            int n = nb * 16 + cl;
            unsigned short v[8];
#pragma unroll
            for (int j = 0; j < 8; j++) {
                int k = kb * 32 + q * 8 + j;
                float f = (k < NIN) ? ldin(w, isbf, (size_t)k * HC + n) : 0.f;
                v[j] = f2us(f);
            }
            ushort4* dst = (ushort4*)(bswz + ((size_t)fb * 64 + lane) * 8);
            dst[0] = make_ushort4(v[0], v[1], v[2], v[3]);
            dst[1] = make_ushort4(v[4], v[5], v[6], v[7]);
        }
    } else {
        int g = threadIdx.x;   // graph start offsets, batch sorted
        int lo = 0, hi = N;
        while (lo < hi) {
            int mid = (lo + hi) >> 1;
            if (batch[mid] < g) lo = mid + 1;
            else hi = mid;
        }
        gs[g] = lo;
        if (g == 0) gs[G] = N;
    }
}

// ---------------- h = x @ lin_w via MFMA; x AND B staged through LDS (R8, kept) ----------------
__global__ __launch_bounds__(256) void k_lin_mfma(const void* __restrict__ x,
                                                  const unsigned short* __restrict__ bswz,
                                                  const void* __restrict__ att_s,
                                                  const void* __restrict__ att_d,
                                                  unsigned short* __restrict__ hb,
                                                  float* __restrict__ a_src,
                                                  float* __restrict__ a_dst,
                                                  const int* __restrict__ flag) {
    __shared__ unsigned short xs[64][XSP];     // 41 KB
    __shared__ unsigned short bs[16 * 64 * 8]; // 16 KB (one kb slab)
    int isbf = *flag;
    int t = threadIdx.x;
    int m0blk = blockIdx.x * 64;
    if (isbf) {
        const unsigned short* xp = (const unsigned short*)x;
        for (int gidx = t; gidx < 64 * 75; gidx += 256) {
            int r = gidx / 75, c = (gidx - r * 75) * 4;
            int row = m0blk + r; if (row >= N) row = N - 1;
            ushort4 v = *(const ushort4*)(xp + (size_t)row * NIN + c);
            *(ushort4*)&xs[r][c] = v;
        }
    } else {
        const float* xp = (const float*)x;
        for (int gidx = t; gidx < 64 * 75; gidx += 256) {
            int r = gidx / 75, c = (gidx - r * 75) * 4;
            int row = m0blk + r; if (row >= N) row = N - 1;
            float4 f = *(const float4*)(xp + (size_t)row * NIN + c);
            *(ushort4*)&xs[r][c] = make_ushort4(f2us(f.x), f2us(f.y), f2us(f.z), f2us(f.w));
        }
    }
    for (int i = t; i < 64 * 28; i += 256) {      // zero K-pad cols 300..327
        int r = i / 28, c = 300 + (i - r * 28);
        xs[r][c] = 0;
    }
    __syncthreads();

    int wave = t >> 6, lane = t & 63;
    int q = lane >> 4, cl = lane & 15;
    int m0 = m0blk + wave * 16;
    const unsigned short* abase = &xs[wave * 16 + cl][q * 8];
    short8 a[NKB];
#pragma unroll
    for (int kb = 0; kb < NKB; kb++) a[kb] = *(const short8*)(abase + kb * 32);
    f32x4 acc[16];
#pragma unroll
    for (int nb = 0; nb < 16; nb++) acc[nb] = f32x4{0.f, 0.f, 0.f, 0.f};
#pragma unroll 1
    for (int kb = 0; kb < NKB; kb++) {
        if (kb) __syncthreads();
        const int4* src = (const int4*)(bswz + (size_t)kb * 16 * 64 * 8);
        int4* dst = (int4*)bs;
#pragma unroll
        for (int j = 0; j < 4; j++) dst[t + 256 * j] = src[t + 256 * j];
        __syncthreads();
        short8 bfr[16];
#pragma unroll
        for (int nb = 0; nb < 16; nb++)
            bfr[nb] = *(const short8*)(bs + ((size_t)nb * 64 + lane) * 8);
#pragma unroll
        for (int nb = 0; nb < 16; nb++)
            acc[nb] = __builtin_amdgcn_mfma_f32_16x16x32_bf16(a[kb], bfr[nb], acc[nb], 0, 0, 0);
    }
    float ps[4][4], pd[4][4];
#pragma unroll
    for (int hh = 0; hh < 4; hh++)
#pragma unroll
        for (int r = 0; r < 4; r++) { ps[hh][r] = 0.f; pd[hh][r] = 0.f; }
#pragma unroll
    for (int nb = 0; nb < 16; nb++) {
        float as_ = ldin(att_s, isbf, nb * 16 + cl);
        float ad_ = ldin(att_d, isbf, nb * 16 + cl);
        int hh = nb >> 2;
#pragma unroll
        for (int r = 0; r < 4; r++) {
            float v = acc[nb][r];
            ps[hh][r] += v * as_;
            pd[hh][r] += v * ad_;
            int gm = m0 + q * 4 + r;
            if (gm < N) hb[(size_t)gm * HC + nb * 16 + cl] = f2us(v);
        }
    }
#pragma unroll
    for (int hh = 0; hh < 4; hh++) {
#pragma unroll
        for (int r = 0; r < 4; r++) {
            float vs = ps[hh][r], vd = pd[hh][r];
#pragma unroll
            for (int m = 1; m < 16; m <<= 1) {
                vs += __shfl_xor(vs, m, 64);
                vd += __shfl_xor(vd, m, 64);
            }
            int gm = m0 + q * 4 + r;
            if (cl == 0 && gm < N) {
                a_src[gm * 4 + hh] = vs;
                a_dst[gm * 4 + hh] = vd;
            }
        }
    }
}

// ---------------- cooperative CSR build: zero | hist | scan | scatter ----------------
__global__ __launch_bounds__(256) void k_csr(const int* __restrict__ ei,
                                             const float* __restrict__ a_src,
                                             const float* __restrict__ a_dst,
                                             int* __restrict__ cnt,
                                             int* __restrict__ bsum,
                                             int* __restrict__ off,
                                             int* __restrict__ cur,
                                             int* __restrict__ csr_s,
                                             float* __restrict__ csr_w) {
    cg::grid_group grid = cg::this_grid();
    __shared__ int sd[256];
    int t = threadIdx.x, b = blockIdx.x;
    int gtid = b * 256 + t, gsz = gridDim.x * 256;   // 262144
    const int* dst = ei + E;
    // phase 0: zero cnt
    for (int i = gtid; i < N; i += gsz) cnt[i] = 0;
    grid.sync();
    // phase 1: degree histogram
    for (int e = gtid; e < E; e += gsz) atomicAdd(&cnt[dst[e]], 1);
    grid.sync();
    // phase 2: per-chunk local exclusive scan
    if (b < NCH) {
        int idx = b * 256 + t;
        int c = (idx < N) ? cnt[idx] : 0;
        sd[t] = c;
        __syncthreads();
        for (int d = 1; d < 256; d <<= 1) {
            int u = (t >= d) ? sd[t - d] : 0;
            __syncthreads();
            sd[t] += u;
            __syncthreads();
        }
        if (idx < N) off[idx] = sd[t] - c;   // local exclusive
        if (t == 255) bsum[b] = sd[255];
    }
    grid.sync();
    // phase 3: block 0 scans the 196 chunk totals
    if (b == 0) {
        int v = (t < NCH) ? bsum[t] : 0;
        sd[t] = v;
        __syncthreads();
        for (int d = 1; d < 256; d <<= 1) {
            int u = (t >= d) ? sd[t - d] : 0;
            __syncthreads();
            sd[t] += u;
            __syncthreads();
        }
        if (t < NCH) bsum[t] = sd[t] - v;    // exclusive chunk offsets
        if (t == 255) off[N] = sd[255];      // total = E
    }
    grid.sync();
    // phase 4: globalize offsets, init cursors
    if (b < NCH) {
        int idx = b * 256 + t;
        if (idx < N) {
            int ex = off[idx] + bsum[b];
            off[idx] = ex;
            cur[idx] = ex;
        }
    }
    grid.sync();
    // phase 5: scatter edges + per-edge softmax weights
    for (int e = gtid; e < E; e += gsz) {
        int s = ei[e], d = dst[e];
        float4 as = *(const float4*)&a_src[(size_t)s * 4];
        float4 ad = *(const float4*)&a_dst[(size_t)d * 4];
        float4 w;
        w.x = __expf(lrelu_att(as.x + ad.x));
        w.y = __expf(lrelu_att(as.y + ad.y));
        w.z = __expf(lrelu_att(as.z + ad.z));
        w.w = __expf(lrelu_att(as.w + ad.w));
        int pos = atomicAdd(&cur[d], 1);
        csr_s[pos] = s;
        *(float4*)&csr_w[(size_t)pos * 4] = w;
    }
}

// ---------------- per-node aggregation (R6 form: measured 63.4 us, VGPR 24) ----------------
__global__ __launch_bounds__(256) void k_agg(const unsigned short* __restrict__ hb,
                                             const float* __restrict__ a_src,
                                             const float* __restrict__ a_dst,
                                             const int* __restrict__ off,
                                             const int* __restrict__ csr_s,
                                             const float* __restrict__ csr_w,
                                             const void* __restrict__ bias,
                                             unsigned short* __restrict__ outn,
                                             const int* __restrict__ flag) {
    int isbf = *flag;
    int wave = threadIdx.x >> 6, lane = threadIdx.x & 63;
    int n = blockIdx.x * 4 + wave;
    if (n >= N) return;
    int head = lane >> 4;
    float wself = __expf(lrelu_att(a_src[n * 4 + head] + a_dst[n * 4 + head]));
    ushort4 hv = *(const ushort4*)&hb[(size_t)n * HC + lane * 4];
    float4 acc;
    acc.x = us2f(hv.x) * wself;
    acc.y = us2f(hv.y) * wself;
    acc.z = us2f(hv.z) * wself;
    acc.w = us2f(hv.w) * wself;
    float ssum = wself;
    int p0 = off[n], p1 = off[n + 1];
    int i0 = 0, i1 = 0, i2 = 0, i3 = 0;
    if (p0 + 4 <= p1) { i0 = csr_s[p0]; i1 = csr_s[p0 + 1]; i2 = csr_s[p0 + 2]; i3 = csr_s[p0 + 3]; }
    int p = p0;
    for (; p + 4 <= p1; p += 4) {
        int s0 = i0, s1 = i1, s2 = i2, s3 = i3;
        ushort4 g0 = *(const ushort4*)&hb[(size_t)s0 * HC + lane * 4];
        ushort4 g1 = *(const ushort4*)&hb[(size_t)s1 * HC + lane * 4];
        ushort4 g2 = *(const ushort4*)&hb[(size_t)s2 * HC + lane * 4];
        ushort4 g3 = *(const ushort4*)&hb[(size_t)s3 * HC + lane * 4];
        float w0 = csr_w[(size_t)(p + 0) * 4 + head];
        float w1 = csr_w[(size_t)(p + 1) * 4 + head];
        float w2 = csr_w[(size_t)(p + 2) * 4 + head];
        float w3 = csr_w[(size_t)(p + 3) * 4 + head];
        int nn = p + 4;
        if (nn + 4 <= p1) { i0 = csr_s[nn]; i1 = csr_s[nn + 1]; i2 = csr_s[nn + 2]; i3 = csr_s[nn + 3]; }
        acc.x += us2f(g0.x) * w0 + us2f(g1.x) * w1 + us2f(g2.x) * w2 + us2f(g3.x) * w3;
        acc.y += us2f(g0.y) * w0 + us2f(g1.y) * w1 + us2f(g2.y) * w2 + us2f(g3.y) * w3;
        acc.z += us2f(g0.z) * w0 + us2f(g1.z) * w1 + us2f(g2.z) * w2 + us2f(g3.z) * w3;
        acc.w += us2f(g0.w) * w0 + us2f(g1.w) * w1 + us2f(g2.w) * w2 + us2f(g3.w) * w3;
        ssum += (w0 + w1) + (w2 + w3);
    }
    for (; p < p1; p++) {
        int s = csr_s[p];
        float wv = csr_w[(size_t)p * 4 + head];
        ushort4 hs = *(const ushort4*)&hb[(size_t)s * HC + lane * 4];
        acc.x += us2f(hs.x) * wv;
        acc.y += us2f(hs.y) * wv;
        acc.z += us2f(hs.z) * wv;
        acc.w += us2f(hs.w) * wv;
        ssum += wv;
    }
    float inv = 1.f / ssum;
    ushort4 o;
    o.x = f2us(lrelu_act(acc.x * inv + ldin(bias, isbf, lane * 4 + 0)));
    o.y = f2us(lrelu_act(acc.y * inv + ldin(bias, isbf, lane * 4 + 1)));
    o.z = f2us(lrelu_act(acc.z * inv + ldin(bias, isbf, lane * 4 + 2)));
    o.w = f2us(lrelu_act(acc.w * inv + ldin(bias, isbf, lane * 4 + 3)));
    *(ushort4*)&outn[(size_t)n * HC + lane * 4] = o;
}

// ---------------- cooperative pool+fc: zero sums | pool atomics | fc ----------------
__global__ __launch_bounds__(256) void k_poolfc(const unsigned short* __restrict__ outn,
                                                const int* __restrict__ gs,
                                                float* __restrict__ sums,
                                                const void* __restrict__ fw,
                                                const void* __restrict__ fb,
                                                void* __restrict__ out,
                                                const int* __restrict__ flag) {
    cg::grid_group grid = cg::this_grid();
    __shared__ float pl[HC];
    int b = blockIdx.x, t = threadIdx.x;
    int isbf = *flag;
    // phase 0: zero sums (G*HC = 65536 floats; 1024 blocks cover 262144)
    int gtid = b * 256 + t;
    if (gtid < G * HC) sums[gtid] = 0.f;
    grid.sync();
    // phase 1: pool — block = (graph, quarter)
    {
        int g = b >> 2, qq = b & 3;
        int s = gs[g], e2 = gs[g + 1];
        int len = e2 - s;
        int r0 = s + (len * qq) / 4;
        int r1 = s + (len * (qq + 1)) / 4;
        float a0 = 0.f, a1 = 0.f, a2 = 0.f, a3 = 0.f;
        int r = r0;
        for (; r + 4 <= r1; r += 4) {
            a0 += us2f(outn[(size_t)(r + 0) * HC + t]);
            a1 += us2f(outn[(size_t)(r + 1) * HC + t]);
            a2 += us2f(outn[(size_t)(r + 2) * HC + t]);
            a3 += us2f(outn[(size_t)(r + 3) * HC + t]);
        }
        for (; r < r1; r++) a0 += us2f(outn[(size_t)r * HC + t]);
        float v = (a0 + a1) + (a2 + a3);
        if (r1 > r0) atomicAdd(&sums[(size_t)g * HC + t], v);
    }
    grid.sync();
    // phase 2: fc — blocks 0..767 = (ob, g)
    if (b < 768) {
        int g = b & 255, ob = b >> 8;      // 768 = 3*256
        int o = ob * 256 + t;
        int c = gs[g + 1] - gs[g];
        float inv = 1.f / (float)(c > 1 ? c : 1);
        pl[t] = sums[(size_t)g * HC + t] * inv;
        __syncthreads();
        float acc = ldin(fb, isbf, o);
#pragma unroll 8
        for (int k = 0; k < HC; k++) acc += pl[k] * ldin(fw, isbf, (size_t)k * NOUT + o);
        size_t oi = (size_t)g * NOUT + o;
        if (isbf) ((bf16*)out)[oi] = __float2bfloat16(acc);
        else      ((float*)out)[oi] = acc;
    }
}

extern "C" void kernel_launch(void* const* d_in, const int* in_sizes, int n_in,
                              void* d_out, int out_size, void* d_ws, size_t ws_size,
                              hipStream_t stream) {
    const void* x     = d_in[0];
    const int*  ei    = (const int*)d_in[1];
    const int*  batch = (const int*)d_in[2];
    const void* lin_w = d_in[3];
    const void* att_s = d_in[4];
    const void* att_d = d_in[5];
    const void* bias  = d_in[6];
    const void* fc1w  = d_in[7];
    const void* fc1b  = d_in[8];

    char* p = (char*)d_ws;
    unsigned short* hb   = (unsigned short*)p; p += (size_t)N * HC * 2;   // 25.6 MB
    unsigned short* outn = (unsigned short*)p; p += (size_t)N * HC * 2;   // 25.6 MB
    float* a_src  = (float*)p; p += (size_t)N * H * 4;
    float* a_dst  = (float*)p; p += (size_t)N * H * 4;
    int* cnt      = (int*)p;   p += (size_t)N * 4;
    float* sums   = (float*)p; p += (size_t)G * HC * 4;
    int* off      = (int*)p;   p += (size_t)(N + 4) * 4;
    int* cur      = (int*)p;   p += (size_t)N * 4;
    int* csr_s    = (int*)p;   p += (size_t)E * 4;                        // 3.2 MB
    float* csr_w  = (float*)p; p += (size_t)E * H * 4;                    // 12.8 MB
    unsigned short* bswz = (unsigned short*)p; p += (size_t)160 * 64 * 8 * 2;
    int* bsum     = (int*)p;   p += 1024;
    int* gs       = (int*)p;   p += (size_t)(G + 4) * 4;
    int* flag     = (int*)p;   p += 16;

    k_pre<<<41, 256, 0, stream>>>((const unsigned short*)x, lin_w, batch, flag, bswz, gs);
    k_lin_mfma<<<MP / 64, 256, 0, stream>>>(x, bswz, att_s, att_d, hb, a_src, a_dst, flag);
    {
        void* args[] = {(void*)&ei, (void*)&a_src, (void*)&a_dst, (void*)&cnt, (void*)&bsum,
                        (void*)&off, (void*)&cur, (void*)&csr_s, (void*)&csr_w};
        hipLaunchCooperativeKernel((void*)k_csr, dim3(1024), dim3(256), args, 0, stream);
    }
    k_agg<<<(N + 3) / 4, 256, 0, stream>>>(hb, a_src, a_dst, off, csr_s, csr_w, bias, outn, flag);
    {
        void* args[] = {(void*)&outn, (void*)&gs, (void*)&sums, (void*)&fc1w, (void*)&fc1b,
                        (void*)&d_out, (void*)&flag};
        hipLaunchCooperativeKernel((void*)k_poolfc, dim3(1024), dim3(256), args, 0, stream);
    }
}

// Round 10
// 352.604 us; speedup vs baseline: 2.7763x; 2.7763x over previous
//
#include <hip/hip_runtime.h>
#include <hip/hip_bf16.h>

using bf16 = __hip_bfloat16;
typedef __attribute__((ext_vector_type(8))) short short8;
typedef __attribute__((ext_vector_type(4))) float f32x4;

constexpr int N   = 50000;
constexpr int E   = 800000;
constexpr int NIN = 300;
constexpr int H   = 4;
constexpr int C   = 64;
constexpr int HC  = H * C;      // 256
constexpr int G   = 256;
constexpr int NOUT = 768;
constexpr int NKB = 10;         // K blocks of 32 (K padded 300->320)
constexpr int MP  = 50048;      // M padded to 782*64
constexpr int XSP = 328;        // LDS row pitch (bf16 elems)

__device__ __forceinline__ float b2f(bf16 v) { return __bfloat162float(v); }
__device__ __forceinline__ float us2f(unsigned short u) {
    bf16 b; *(unsigned short*)&b = u; return __bfloat162float(b);
}
__device__ __forceinline__ unsigned short f2us(float f) {
    bf16 b = __float2bfloat16(f); return *(unsigned short*)&b;
}
__device__ __forceinline__ float lrelu_att(float v) { return v > 0.f ? v : 0.2f * v; }
__device__ __forceinline__ float lrelu_act(float v) { return v > 0.f ? v : 0.01f * v; }
__device__ __forceinline__ float ldin(const void* p, int isbf, size_t i) {
    return isbf ? b2f(((const bf16*)p)[i]) : ((const float*)p)[i];
}

// in-block dtype detection (reads first 256 uint16s of x; deterministic)
__device__ __forceinline__ int block_detect(const unsigned short* __restrict__ xr) {
    __shared__ int cnt_s;
    if (threadIdx.x == 0) cnt_s = 0;
    __syncthreads();
    unsigned short u = xr[threadIdx.x & 255];
    int ex = (u >> 7) & 0xFF;
    int ok = (ex == 0) || (ex >= 100 && ex <= 140);
    if (threadIdx.x < 256) atomicAdd(&cnt_s, ok);
    __syncthreads();
    return (cnt_s >= 240) ? 1 : 0;   // 1 = bf16 inputs
}

// ---------------- pre: zero cnt+sums | detect | swizzle w | graph ranges ----------------
constexpr int NZ  = N + G * HC;            // ints to zero (cnt + sums)
constexpr int NZB = (NZ + 255) / 256;      // 452
__global__ __launch_bounds__(256) void k_pre(const unsigned short* __restrict__ xr,
                                             const void* __restrict__ w,
                                             const int* __restrict__ batch,
                                             int* __restrict__ flag,
                                             int* __restrict__ zp,
                                             unsigned short* __restrict__ bswz,
                                             int* __restrict__ gs) {
    int b = blockIdx.x;
    if (b < NZB) {
        int i = b * 256 + threadIdx.x;
        if (i < NZ) zp[i] = 0;
        if (b == 0) {
            int isbf = block_detect(xr);
            if (threadIdx.x == 0) *flag = isbf;
        }
    } else if (b < NZB + 40) {
        int isbf = block_detect(xr);
        int fb = (b - NZB) * 4 + (threadIdx.x >> 6);   // kb*16+nb, 0..159
        if (fb < 160) {
            int kb = fb >> 4, nb = fb & 15;
            int lane = threadIdx.x & 63;
            int q = lane >> 4, cl = lane & 15;
            int n = nb * 16 + cl;
            unsigned short v[8];
#pragma unroll
            for (int j = 0; j < 8; j++) {
                int k = kb * 32 + q * 8 + j;
                float f = (k < NIN) ? ldin(w, isbf, (size_t)k * HC + n) : 0.f;
                v[j] = f2us(f);
            }
            ushort4* dst = (ushort4*)(bswz + ((size_t)fb * 64 + lane) * 8);
            dst[0] = make_ushort4(v[0], v[1], v[2], v[3]);
            dst[1] = make_ushort4(v[4], v[5], v[6], v[7]);
        }
    } else {
        int g = threadIdx.x;   // graph start offsets, batch sorted
        int lo = 0, hi = N;
        while (lo < hi) {
            int mid = (lo + hi) >> 1;
            if (batch[mid] < g) lo = mid + 1;
            else hi = mid;
        }
        gs[g] = lo;
        if (g == 0) gs[G] = N;
    }
}

// ---------------- h = x @ lin_w via MFMA; x AND B staged through LDS (R8 form) ----------------
__global__ __launch_bounds__(256) void k_lin_mfma(const void* __restrict__ x,
                                                  const unsigned short* __restrict__ bswz,
                                                  const void* __restrict__ att_s,
                                                  const void* __restrict__ att_d,
                                                  unsigned short* __restrict__ hb,
                                                  float* __restrict__ a_src,
                                                  float* __restrict__ a_dst,
                                                  const int* __restrict__ flag) {
    __shared__ unsigned short xs[64][XSP];     // 41 KB
    __shared__ unsigned short bs[16 * 64 * 8]; // 16 KB (one kb slab)
    int isbf = *flag;
    int t = threadIdx.x;
    int m0blk = blockIdx.x * 64;
    if (isbf) {
        const unsigned short* xp = (const unsigned short*)x;
        for (int gidx = t; gidx < 64 * 75; gidx += 256) {
            int r = gidx / 75, c = (gidx - r * 75) * 4;
            int row = m0blk + r; if (row >= N) row = N - 1;
            ushort4 v = *(const ushort4*)(xp + (size_t)row * NIN + c);
            *(ushort4*)&xs[r][c] = v;
        }
    } else {
        const float* xp = (const float*)x;
        for (int gidx = t; gidx < 64 * 75; gidx += 256) {
            int r = gidx / 75, c = (gidx - r * 75) * 4;
            int row = m0blk + r; if (row >= N) row = N - 1;
            float4 f = *(const float4*)(xp + (size_t)row * NIN + c);
            *(ushort4*)&xs[r][c] = make_ushort4(f2us(f.x), f2us(f.y), f2us(f.z), f2us(f.w));
        }
    }
    for (int i = t; i < 64 * 28; i += 256) {      // zero K-pad cols 300..327
        int r = i / 28, c = 300 + (i - r * 28);
        xs[r][c] = 0;
    }
    __syncthreads();

    int wave = t >> 6, lane = t & 63;
    int q = lane >> 4, cl = lane & 15;
    int m0 = m0blk + wave * 16;
    const unsigned short* abase = &xs[wave * 16 + cl][q * 8];
    short8 a[NKB];
#pragma unroll
    for (int kb = 0; kb < NKB; kb++) a[kb] = *(const short8*)(abase + kb * 32);
    f32x4 acc[16];
#pragma unroll
    for (int nb = 0; nb < 16; nb++) acc[nb] = f32x4{0.f, 0.f, 0.f, 0.f};
#pragma unroll 1
    for (int kb = 0; kb < NKB; kb++) {
        if (kb) __syncthreads();
        const int4* src = (const int4*)(bswz + (size_t)kb * 16 * 64 * 8);
        int4* dst = (int4*)bs;
#pragma unroll
        for (int j = 0; j < 4; j++) dst[t + 256 * j] = src[t + 256 * j];
        __syncthreads();
        short8 bfr[16];
#pragma unroll
        for (int nb = 0; nb < 16; nb++)
            bfr[nb] = *(const short8*)(bs + ((size_t)nb * 64 + lane) * 8);
#pragma unroll
        for (int nb = 0; nb < 16; nb++)
            acc[nb] = __builtin_amdgcn_mfma_f32_16x16x32_bf16(a[kb], bfr[nb], acc[nb], 0, 0, 0);
    }
    float ps[4][4], pd[4][4];
#pragma unroll
    for (int hh = 0; hh < 4; hh++)
#pragma unroll
        for (int r = 0; r < 4; r++) { ps[hh][r] = 0.f; pd[hh][r] = 0.f; }
#pragma unroll
    for (int nb = 0; nb < 16; nb++) {
        float as_ = ldin(att_s, isbf, nb * 16 + cl);
        float ad_ = ldin(att_d, isbf, nb * 16 + cl);
        int hh = nb >> 2;
#pragma unroll
        for (int r = 0; r < 4; r++) {
            float v = acc[nb][r];
            ps[hh][r] += v * as_;
            pd[hh][r] += v * ad_;
            int gm = m0 + q * 4 + r;
            if (gm < N) hb[(size_t)gm * HC + nb * 16 + cl] = f2us(v);
        }
    }
#pragma unroll
    for (int hh = 0; hh < 4; hh++) {
#pragma unroll
        for (int r = 0; r < 4; r++) {
            float vs = ps[hh][r], vd = pd[hh][r];
#pragma unroll
            for (int m = 1; m < 16; m <<= 1) {
                vs += __shfl_xor(vs, m, 64);
                vd += __shfl_xor(vd, m, 64);
            }
            int gm = m0 + q * 4 + r;
            if (cl == 0 && gm < N) {
                a_src[gm * 4 + hh] = vs;
                a_dst[gm * 4 + hh] = vd;
            }
        }
    }
}

// ---------------- degree histogram ----------------
__global__ void k_hist(const int* __restrict__ dst, int* __restrict__ cnt) {
    int e = blockIdx.x * 256 + threadIdx.x;
    if (e < E) atomicAdd(&cnt[dst[e]], 1);
}

// ---------------- scan phase 1: per-block sums ----------------
__global__ __launch_bounds__(256) void k_scan1(const int* __restrict__ cnt, int* __restrict__ bsum) {
    __shared__ int wsum[4];
    int idx = blockIdx.x * 256 + threadIdx.x;
    int v = (idx < N) ? cnt[idx] : 0;
#pragma unroll
    for (int o2 = 32; o2; o2 >>= 1) v += __shfl_down(v, o2, 64);
    if ((threadIdx.x & 63) == 0) wsum[threadIdx.x >> 6] = v;
    __syncthreads();
    if (threadIdx.x == 0) bsum[blockIdx.x] = wsum[0] + wsum[1] + wsum[2] + wsum[3];
}

// ---------------- scan phases 2+3 merged ----------------
__global__ __launch_bounds__(256) void k_scan23(const int* __restrict__ bsum, int nb,
                                                const int* __restrict__ cnt,
                                                int* __restrict__ off, int* __restrict__ cur) {
    __shared__ int sd[256];
    __shared__ int s_boff;
    int t = threadIdx.x;
    int v = (t < nb) ? bsum[t] : 0;
    sd[t] = v;
    __syncthreads();
    for (int d = 1; d < 256; d <<= 1) {
        int u = (t >= d) ? sd[t - d] : 0;
        __syncthreads();
        sd[t] += u;
        __syncthreads();
    }
    if (t == (int)blockIdx.x) s_boff = sd[t] - v;
    if (blockIdx.x == 0 && t == nb - 1) off[N] = sd[t];
    __syncthreads();
    int boff = s_boff;
    int idx = blockIdx.x * 256 + t;
    int c = (idx < N) ? cnt[idx] : 0;
    __syncthreads();
    sd[t] = c;
    __syncthreads();
    for (int d = 1; d < 256; d <<= 1) {
        int u = (t >= d) ? sd[t - d] : 0;
        __syncthreads();
        sd[t] += u;
        __syncthreads();
    }
    int ex = sd[t] - c + boff;
    if (idx < N) { off[idx] = ex; cur[idx] = ex; }
}

// ---------------- scatter edges into CSR + per-edge softmax weights (R6 form) ----------------
__global__ void k_scatter(const int* __restrict__ ei,
                          const float* __restrict__ a_src,
                          const float* __restrict__ a_dst,
                          int* __restrict__ cur,
                          int* __restrict__ csr_s,
                          float* __restrict__ csr_w) {
    int e = blockIdx.x * 256 + threadIdx.x;
    if (e >= E) return;
    int s = ei[e], d = ei[E + e];
    float4 as = *(const float4*)&a_src[(size_t)s * 4];
    float4 ad = *(const float4*)&a_dst[(size_t)d * 4];
    float4 w;
    w.x = __expf(lrelu_att(as.x + ad.x));
    w.y = __expf(lrelu_att(as.y + ad.y));
    w.z = __expf(lrelu_att(as.z + ad.z));
    w.w = __expf(lrelu_att(as.w + ad.w));
    int pos = atomicAdd(&cur[d], 1);
    csr_s[pos] = s;
    *(float4*)&csr_w[(size_t)pos * 4] = w;
}

// ---------------- per-node aggregation (R6 form: measured 63.4 us, VGPR 24) ----------------
__global__ __launch_bounds__(256) void k_agg(const unsigned short* __restrict__ hb,
                                             const float* __restrict__ a_src,
                                             const float* __restrict__ a_dst,
                                             const int* __restrict__ off,
                                             const int* __restrict__ csr_s,
                                             const float* __restrict__ csr_w,
                                             const void* __restrict__ bias,
                                             unsigned short* __restrict__ outn,
                                             const int* __restrict__ flag) {
    int isbf = *flag;
    int wave = threadIdx.x >> 6, lane = threadIdx.x & 63;
    int n = blockIdx.x * 4 + wave;
    if (n >= N) return;
    int head = lane >> 4;
    float wself = __expf(lrelu_att(a_src[n * 4 + head] + a_dst[n * 4 + head]));
    ushort4 hv = *(const ushort4*)&hb[(size_t)n * HC + lane * 4];
    float4 acc;
    acc.x = us2f(hv.x) * wself;
    acc.y = us2f(hv.y) * wself;
    acc.z = us2f(hv.z) * wself;
    acc.w = us2f(hv.w) * wself;
    float ssum = wself;
    int p0 = off[n], p1 = off[n + 1];
    int i0 = 0, i1 = 0, i2 = 0, i3 = 0;
    if (p0 + 4 <= p1) { i0 = csr_s[p0]; i1 = csr_s[p0 + 1]; i2 = csr_s[p0 + 2]; i3 = csr_s[p0 + 3]; }
    int p = p0;
    for (; p + 4 <= p1; p += 4) {
        int s0 = i0, s1 = i1, s2 = i2, s3 = i3;
        ushort4 g0 = *(const ushort4*)&hb[(size_t)s0 * HC + lane * 4];
        ushort4 g1 = *(const ushort4*)&hb[(size_t)s1 * HC + lane * 4];
        ushort4 g2 = *(const ushort4*)&hb[(size_t)s2 * HC + lane * 4];
        ushort4 g3 = *(const ushort4*)&hb[(size_t)s3 * HC + lane * 4];
        float w0 = csr_w[(size_t)(p + 0) * 4 + head];
        float w1 = csr_w[(size_t)(p + 1) * 4 + head];
        float w2 = csr_w[(size_t)(p + 2) * 4 + head];
        float w3 = csr_w[(size_t)(p + 3) * 4 + head];
        int nn = p + 4;
        if (nn + 4 <= p1) { i0 = csr_s[nn]; i1 = csr_s[nn + 1]; i2 = csr_s[nn + 2]; i3 = csr_s[nn + 3]; }
        acc.x += us2f(g0.x) * w0 + us2f(g1.x) * w1 + us2f(g2.x) * w2 + us2f(g3.x) * w3;
        acc.y += us2f(g0.y) * w0 + us2f(g1.y) * w1 + us2f(g2.y) * w2 + us2f(g3.y) * w3;
        acc.z += us2f(g0.z) * w0 + us2f(g1.z) * w1 + us2f(g2.z) * w2 + us2f(g3.z) * w3;
        acc.w += us2f(g0.w) * w0 + us2f(g1.w) * w1 + us2f(g2.w) * w2 + us2f(g3.w) * w3;
        ssum += (w0 + w1) + (w2 + w3);
    }
    for (; p < p1; p++) {
        int s = csr_s[p];
        float wv = csr_w[(size_t)p * 4 + head];
        ushort4 hs = *(const ushort4*)&hb[(size_t)s * HC + lane * 4];
        acc.x += us2f(hs.x) * wv;
        acc.y += us2f(hs.y) * wv;
        acc.z += us2f(hs.z) * wv;
        acc.w += us2f(hs.w) * wv;
        ssum += wv;
    }
    float inv = 1.f / ssum;
    ushort4 o;
    o.x = f2us(lrelu_act(acc.x * inv + ldin(bias, isbf, lane * 4 + 0)));
    o.y = f2us(lrelu_act(acc.y * inv + ldin(bias, isbf, lane * 4 + 1)));
    o.z = f2us(lrelu_act(acc.z * inv + ldin(bias, isbf, lane * 4 + 2)));
    o.w = f2us(lrelu_act(acc.w * inv + ldin(bias, isbf, lane * 4 + 3)));
    *(ushort4*)&outn[(size_t)n * HC + lane * 4] = o;
}

// ---------------- pooling: (graph, quarter) grid ----------------
__global__ __launch_bounds__(256) void k_pool2(const unsigned short* __restrict__ outn,
                                               const int* __restrict__ gs,
                                               float* __restrict__ sums) {
    int g = blockIdx.x, qq = blockIdx.y, t = threadIdx.x;
    int s = gs[g], e2 = gs[g + 1];
    int len = e2 - s;
    int r0 = s + (len * qq) / 4;
    int r1 = s + (len * (qq + 1)) / 4;
    float a0 = 0.f, a1 = 0.f, a2 = 0.f, a3 = 0.f;
    int r = r0;
    for (; r + 4 <= r1; r += 4) {
        a0 += us2f(outn[(size_t)(r + 0) * HC + t]);
        a1 += us2f(outn[(size_t)(r + 1) * HC + t]);
        a2 += us2f(outn[(size_t)(r + 2) * HC + t]);
        a3 += us2f(outn[(size_t)(r + 3) * HC + t]);
    }
    for (; r < r1; r++) a0 += us2f(outn[(size_t)r * HC + t]);
    float v = (a0 + a1) + (a2 + a3);
    if (r1 > r0) atomicAdd(&sums[(size_t)g * HC + t], v);
}

// ---------------- final FC (mean-divide folded in, dual-dtype out) ----------------
__global__ __launch_bounds__(256) void k_fc(const float* __restrict__ sums,
                                            const int* __restrict__ gs,
                                            const void* __restrict__ fw,
                                            const void* __restrict__ fb,
                                            void* __restrict__ out,
                                            const int* __restrict__ flag) {
    __shared__ float pl[HC];
    int isbf = *flag;
    int g = blockIdx.y;
    int o = blockIdx.x * 256 + threadIdx.x;
    int c = gs[g + 1] - gs[g];
    float inv = 1.f / (float)(c > 1 ? c : 1);
    pl[threadIdx.x] = sums[(size_t)g * HC + threadIdx.x] * inv;
    __syncthreads();
    float acc = ldin(fb, isbf, o);
#pragma unroll 8
    for (int k = 0; k < HC; k++) acc += pl[k] * ldin(fw, isbf, (size_t)k * NOUT + o);
    size_t oi = (size_t)g * NOUT + o;
    if (isbf) ((bf16*)out)[oi] = __float2bfloat16(acc);
    else      ((float*)out)[oi] = acc;
}

extern "C" void kernel_launch(void* const* d_in, const int* in_sizes, int n_in,
                              void* d_out, int out_size, void* d_ws, size_t ws_size,
                              hipStream_t stream) {
    const void* x     = d_in[0];
    const int*  ei    = (const int*)d_in[1];
    const int*  batch = (const int*)d_in[2];
    const void* lin_w = d_in[3];
    const void* att_s = d_in[4];
    const void* att_d = d_in[5];
    const void* bias  = d_in[6];
    const void* fc1w  = d_in[7];
    const void* fc1b  = d_in[8];

    char* p = (char*)d_ws;
    unsigned short* hb   = (unsigned short*)p; p += (size_t)N * HC * 2;   // 25.6 MB
    unsigned short* outn = (unsigned short*)p; p += (size_t)N * HC * 2;   // 25.6 MB
    float* a_src  = (float*)p; p += (size_t)N * H * 4;
    float* a_dst  = (float*)p; p += (size_t)N * H * 4;
    int* cnt      = (int*)p;   p += (size_t)N * 4;                        // cnt+sums zeroed together
    float* sums   = (float*)p; p += (size_t)G * HC * 4;
    int* off      = (int*)p;   p += (size_t)(N + 4) * 4;
    int* cur      = (int*)p;   p += (size_t)N * 4;
    int* csr_s    = (int*)p;   p += (size_t)E * 4;                        // 3.2 MB
    float* csr_w  = (float*)p; p += (size_t)E * H * 4;                    // 12.8 MB
    unsigned short* bswz = (unsigned short*)p; p += (size_t)160 * 64 * 8 * 2;
    int* bsum     = (int*)p;   p += 1024;
    int* gs       = (int*)p;   p += (size_t)(G + 4) * 4;
    int* flag     = (int*)p;   p += 16;

    const int NB = (N + 255) / 256;  // 196

    k_pre<<<NZB + 40 + 1, 256, 0, stream>>>((const unsigned short*)x, lin_w, batch,
                                            flag, cnt, bswz, gs);
    k_lin_mfma<<<MP / 64, 256, 0, stream>>>(x, bswz, att_s, att_d, hb, a_src, a_dst, flag);
    k_hist<<<(E + 255) / 256, 256, 0, stream>>>(ei + E, cnt);
    k_scan1<<<NB, 256, 0, stream>>>(cnt, bsum);
    k_scan23<<<NB, 256, 0, stream>>>(bsum, NB, cnt, off, cur);
    k_scatter<<<(E + 255) / 256, 256, 0, stream>>>(ei, a_src, a_dst, cur, csr_s, csr_w);
    k_agg<<<(N + 3) / 4, 256, 0, stream>>>(hb, a_src, a_dst, off, csr_s, csr_w, bias, outn, flag);
    k_pool2<<<dim3(G, 4), 256, 0, stream>>>(outn, gs, sums);
    k_fc<<<dim3(NOUT / 256, G), 256, 0, stream>>>(sums, gs, fc1w, fc1b, d_out, flag);
}

// Round 11
// 345.795 us; speedup vs baseline: 2.8310x; 1.0197x over previous
//
#include <hip/hip_runtime.h>
#include <hip/hip_bf16.h>

using bf16 = __hip_bfloat16;
typedef __attribute__((ext_vector_type(8))) short short8;
typedef __attribute__((ext_vector_type(4))) float f32x4;

constexpr int N   = 50000;
constexpr int E   = 800000;
constexpr int NIN = 300;
constexpr int H   = 4;
constexpr int C   = 64;
constexpr int HC  = H * C;      // 256
constexpr int G   = 256;
constexpr int NOUT = 768;
constexpr int NKB = 10;         // K blocks of 32 (K padded 300->320)
constexpr int NT  = 782;        // row tiles of 64 (50048 rows)

__device__ __forceinline__ float b2f(bf16 v) { return __bfloat162float(v); }
__device__ __forceinline__ float us2f(unsigned short u) {
    bf16 b; *(unsigned short*)&b = u; return __bfloat162float(b);
}
__device__ __forceinline__ unsigned short f2us(float f) {
    bf16 b = __float2bfloat16(f); return *(unsigned short*)&b;
}
__device__ __forceinline__ float lrelu_att(float v) { return v > 0.f ? v : 0.2f * v; }
__device__ __forceinline__ float lrelu_act(float v) { return v > 0.f ? v : 0.01f * v; }
__device__ __forceinline__ float ldin(const void* p, int isbf, size_t i) {
    return isbf ? b2f(((const bf16*)p)[i]) : ((const float*)p)[i];
}
__device__ __forceinline__ short8 pack8u(ushort4 lo, ushort4 hi) {
    short8 r;
    r[0] = (short)lo.x; r[1] = (short)lo.y; r[2] = (short)lo.z; r[3] = (short)lo.w;
    r[4] = (short)hi.x; r[5] = (short)hi.y; r[6] = (short)hi.z; r[7] = (short)hi.w;
    return r;
}
__device__ __forceinline__ short8 pack8f(float4 lo, float4 hi) {
    short8 r;
    r[0] = (short)f2us(lo.x); r[1] = (short)f2us(lo.y); r[2] = (short)f2us(lo.z); r[3] = (short)f2us(lo.w);
    r[4] = (short)f2us(hi.x); r[5] = (short)f2us(hi.y); r[6] = (short)f2us(hi.z); r[7] = (short)f2us(hi.w);
    return r;
}

// in-block dtype detection (reads first 256 uint16s of x; deterministic)
__device__ __forceinline__ int block_detect(const unsigned short* __restrict__ xr) {
    __shared__ int cnt_s;
    if (threadIdx.x == 0) cnt_s = 0;
    __syncthreads();
    unsigned short u = xr[threadIdx.x & 255];
    int ex = (u >> 7) & 0xFF;
    int ok = (ex == 0) || (ex >= 100 && ex <= 140);
    if (threadIdx.x < 256) atomicAdd(&cnt_s, ok);
    __syncthreads();
    return (cnt_s >= 240) ? 1 : 0;   // 1 = bf16 inputs
}

// ---------------- pre: zero cnt+sums | detect | swizzle w | graph ranges ----------------
constexpr int NZ  = N + G * HC;            // ints to zero (cnt + sums)
constexpr int NZB = (NZ + 255) / 256;      // 452
__global__ __launch_bounds__(256) void k_pre(const unsigned short* __restrict__ xr,
                                             const void* __restrict__ w,
                                             const int* __restrict__ batch,
                                             int* __restrict__ flag,
                                             int* __restrict__ zp,
                                             unsigned short* __restrict__ bswz,
                                             int* __restrict__ gs) {
    int b = blockIdx.x;
    if (b < NZB) {
        int i = b * 256 + threadIdx.x;
        if (i < NZ) zp[i] = 0;
        if (b == 0) {
            int isbf = block_detect(xr);
            if (threadIdx.x == 0) *flag = isbf;
        }
    } else if (b < NZB + 40) {
        int isbf = block_detect(xr);
        int fb = (b - NZB) * 4 + (threadIdx.x >> 6);   // kb*16+nb, 0..159
        if (fb < 160) {
            int kb = fb >> 4, nb = fb & 15;
            int lane = threadIdx.x & 63;
            int q = lane >> 4, cl = lane & 15;
            int n = nb * 16 + cl;
            unsigned short v[8];
#pragma unroll
            for (int j = 0; j < 8; j++) {
                int k = kb * 32 + q * 8 + j;
                float f = (k < NIN) ? ldin(w, isbf, (size_t)k * HC + n) : 0.f;
                v[j] = f2us(f);
            }
            ushort4* dst = (ushort4*)(bswz + ((size_t)fb * 64 + lane) * 8);
            dst[0] = make_ushort4(v[0], v[1], v[2], v[3]);
            dst[1] = make_ushort4(v[4], v[5], v[6], v[7]);
        }
    } else {
        int g = threadIdx.x;   // graph start offsets, batch sorted
        int lo = 0, hi = N;
        while (lo < hi) {
            int mid = (lo + hi) >> 1;
            if (batch[mid] < g) lo = mid + 1;
            else hi = mid;
        }
        gs[g] = lo;
        if (g == 0) gs[G] = N;
    }
}

// ---------------- h = x @ lin_w via MFMA; B-half resident in LDS, A direct from global ----------------
// Each block owns half the 256 output cols (80 KB of swizzled B in LDS, staged ONCE).
// Tile loop has NO barriers: A-frags global->regs, B via ds_read_b128, MFMA, epilogue.
// Col halves own complete heads (half0: h0,h1; half1: h2,h3) -> no cross-half combine.
__global__ __launch_bounds__(256) void k_lin2(const void* __restrict__ x,
                                              const unsigned short* __restrict__ bswz,
                                              const void* __restrict__ att_s,
                                              const void* __restrict__ att_d,
                                              unsigned short* __restrict__ hb,
                                              float* __restrict__ a_src,
                                              float* __restrict__ a_dst,
                                              const int* __restrict__ flag) {
    __shared__ unsigned short bs[80 * 64 * 8];   // 80 KB: 10 kb x 8 nb fragments
    int isbf = *flag;
    int t = threadIdx.x;
    int half  = blockIdx.x >> 8;    // 512 blocks: 0..255 -> half 0, 256..511 -> half 1
    int bslot = blockIdx.x & 255;
    // ---- stage this half of B into LDS once (5120 int4, 20 per thread) ----
    for (int i = t; i < 80 * 64; i += 256) {
        int f = i >> 6, lane = i & 63;
        int kb = f >> 3, nbl = f & 7;
        const int4* src = (const int4*)(bswz + ((size_t)(kb * 16 + half * 8 + nbl) * 64 + lane) * 8);
        ((int4*)bs)[i] = *src;
    }
    __syncthreads();

    int wave = t >> 6, lane = t & 63;
    int q = lane >> 4, cl = lane & 15;
    for (int tile = bslot; tile < NT; tile += 256) {
        int m0 = tile * 64 + wave * 16;
        int row = m0 + cl; if (row >= N) row = N - 1;
        short8 a[NKB];
        if (isbf) {
            const unsigned short* xr = (const unsigned short*)x + (size_t)row * NIN + q * 8;
#pragma unroll
            for (int kb = 0; kb < 9; kb++) {
                ushort4 lo = *(const ushort4*)(xr + kb * 32);
                ushort4 hi = *(const ushort4*)(xr + kb * 32 + 4);
                a[kb] = pack8u(lo, hi);
            }
            ushort4 z = make_ushort4(0, 0, 0, 0);
            ushort4 lo = z, hi = z;
            if (q == 0)      { lo = *(const ushort4*)(xr + 288); hi = *(const ushort4*)(xr + 292); }
            else if (q == 1) { lo = *(const ushort4*)(xr + 288); }   // k=296..299
            a[9] = pack8u(lo, hi);
        } else {
            const float* xf = (const float*)x + (size_t)row * NIN + q * 8;
#pragma unroll
            for (int kb = 0; kb < 9; kb++) {
                float4 lo = *(const float4*)(xf + kb * 32);
                float4 hi = *(const float4*)(xf + kb * 32 + 4);
                a[kb] = pack8f(lo, hi);
            }
            float4 zf = make_float4(0.f, 0.f, 0.f, 0.f);
            float4 lo = zf, hi = zf;
            if (q == 0)      { lo = *(const float4*)(xf + 288); hi = *(const float4*)(xf + 292); }
            else if (q == 1) { lo = *(const float4*)(xf + 288); }
            a[9] = pack8f(lo, hi);
        }
        f32x4 acc[8];
#pragma unroll
        for (int nbl = 0; nbl < 8; nbl++) acc[nbl] = f32x4{0.f, 0.f, 0.f, 0.f};
#pragma unroll
        for (int kb = 0; kb < NKB; kb++) {
            short8 bfr[8];
#pragma unroll
            for (int nbl = 0; nbl < 8; nbl++)
                bfr[nbl] = *(const short8*)(bs + ((size_t)(kb * 8 + nbl) * 64 + lane) * 8);
#pragma unroll
            for (int nbl = 0; nbl < 8; nbl++)
                acc[nbl] = __builtin_amdgcn_mfma_f32_16x16x32_bf16(a[kb], bfr[nbl], acc[nbl], 0, 0, 0);
        }
        // epilogue: store h (bf16) + attention partials for this half's 2 heads
        float ps[2][4], pd[2][4];
#pragma unroll
        for (int lh = 0; lh < 2; lh++)
#pragma unroll
            for (int r = 0; r < 4; r++) { ps[lh][r] = 0.f; pd[lh][r] = 0.f; }
#pragma unroll
        for (int nbl = 0; nbl < 8; nbl++) {
            int nb = half * 8 + nbl;
            float as_ = ldin(att_s, isbf, nb * 16 + cl);
            float ad_ = ldin(att_d, isbf, nb * 16 + cl);
            int lh = nbl >> 2;
#pragma unroll
            for (int r = 0; r < 4; r++) {
                float v = acc[nbl][r];
                ps[lh][r] += v * as_;
                pd[lh][r] += v * ad_;
                int gm = m0 + q * 4 + r;
                if (gm < N) hb[(size_t)gm * HC + nb * 16 + cl] = f2us(v);
            }
        }
#pragma unroll
        for (int lh = 0; lh < 2; lh++) {
            int hh = half * 2 + lh;
#pragma unroll
            for (int r = 0; r < 4; r++) {
                float vs = ps[lh][r], vd = pd[lh][r];
#pragma unroll
                for (int m = 1; m < 16; m <<= 1) {
                    vs += __shfl_xor(vs, m, 64);
                    vd += __shfl_xor(vd, m, 64);
                }
                int gm = m0 + q * 4 + r;
                if (cl == 0 && gm < N) {
                    a_src[gm * 4 + hh] = vs;
                    a_dst[gm * 4 + hh] = vd;
                }
            }
        }
    }
}

// ---------------- degree histogram ----------------
__global__ void k_hist(const int* __restrict__ dst, int* __restrict__ cnt) {
    int e = blockIdx.x * 256 + threadIdx.x;
    if (e < E) atomicAdd(&cnt[dst[e]], 1);
}

// ---------------- scan phase 1: per-block sums ----------------
__global__ __launch_bounds__(256) void k_scan1(const int* __restrict__ cnt, int* __restrict__ bsum) {
    __shared__ int wsum[4];
    int idx = blockIdx.x * 256 + threadIdx.x;
    int v = (idx < N) ? cnt[idx] : 0;
#pragma unroll
    for (int o2 = 32; o2; o2 >>= 1) v += __shfl_down(v, o2, 64);
    if ((threadIdx.x & 63) == 0) wsum[threadIdx.x >> 6] = v;
    __syncthreads();
    if (threadIdx.x == 0) bsum[blockIdx.x] = wsum[0] + wsum[1] + wsum[2] + wsum[3];
}

// ---------------- scan phases 2+3 merged ----------------
__global__ __launch_bounds__(256) void k_scan23(const int* __restrict__ bsum, int nb,
                                                const int* __restrict__ cnt,
                                                int* __restrict__ off, int* __restrict__ cur) {
    __shared__ int sd[256];
    __shared__ int s_boff;
    int t = threadIdx.x;
    int v = (t < nb) ? bsum[t] : 0;
    sd[t] = v;
    __syncthreads();
    for (int d = 1; d < 256; d <<= 1) {
        int u = (t >= d) ? sd[t - d] : 0;
        __syncthreads();
        sd[t] += u;
        __syncthreads();
    }
    if (t == (int)blockIdx.x) s_boff = sd[t] - v;
    if (blockIdx.x == 0 && t == nb - 1) off[N] = sd[t];
    __syncthreads();
    int boff = s_boff;
    int idx = blockIdx.x * 256 + t;
    int c = (idx < N) ? cnt[idx] : 0;
    __syncthreads();
    sd[t] = c;
    __syncthreads();
    for (int d = 1; d < 256; d <<= 1) {
        int u = (t >= d) ? sd[t - d] : 0;
        __syncthreads();
        sd[t] += u;
        __syncthreads();
    }
    int ex = sd[t] - c + boff;
    if (idx < N) { off[idx] = ex; cur[idx] = ex; }
}

// ---------------- scatter edges into CSR + per-edge softmax weights ----------------
__global__ void k_scatter(const int* __restrict__ ei,
                          const float* __restrict__ a_src,
                          const float* __restrict__ a_dst,
                          int* __restrict__ cur,
                          int* __restrict__ csr_s,
                          float* __restrict__ csr_w) {
    int e = blockIdx.x * 256 + threadIdx.x;
    if (e >= E) return;
    int s = ei[e], d = ei[E + e];
    float4 as = *(const float4*)&a_src[(size_t)s * 4];
    float4 ad = *(const float4*)&a_dst[(size_t)d * 4];
    float4 w;
    w.x = __expf(lrelu_att(as.x + ad.x));
    w.y = __expf(lrelu_att(as.y + ad.y));
    w.z = __expf(lrelu_att(as.z + ad.z));
    w.w = __expf(lrelu_att(as.w + ad.w));
    int pos = atomicAdd(&cur[d], 1);
    csr_s[pos] = s;
    *(float4*)&csr_w[(size_t)pos * 4] = w;
}

// ---------------- per-node aggregation (R6 form: measured 63.4 us, VGPR 24) ----------------
__global__ __launch_bounds__(256) void k_agg(const unsigned short* __restrict__ hb,
                                             const float* __restrict__ a_src,
                                             const float* __restrict__ a_dst,
                                             const int* __restrict__ off,
                                             const int* __restrict__ csr_s,
                                             const float* __restrict__ csr_w,
                                             const void* __restrict__ bias,
                                             unsigned short* __restrict__ outn,
                                             const int* __restrict__ flag) {
    int isbf = *flag;
    int wave = threadIdx.x >> 6, lane = threadIdx.x & 63;
    int n = blockIdx.x * 4 + wave;
    if (n >= N) return;
    int head = lane >> 4;
    float wself = __expf(lrelu_att(a_src[n * 4 + head] + a_dst[n * 4 + head]));
    ushort4 hv = *(const ushort4*)&hb[(size_t)n * HC + lane * 4];
    float4 acc;
    acc.x = us2f(hv.x) * wself;
    acc.y = us2f(hv.y) * wself;
    acc.z = us2f(hv.z) * wself;
    acc.w = us2f(hv.w) * wself;
    float ssum = wself;
    int p0 = off[n], p1 = off[n + 1];
    int i0 = 0, i1 = 0, i2 = 0, i3 = 0;
    if (p0 + 4 <= p1) { i0 = csr_s[p0]; i1 = csr_s[p0 + 1]; i2 = csr_s[p0 + 2]; i3 = csr_s[p0 + 3]; }
    int p = p0;
    for (; p + 4 <= p1; p += 4) {
        int s0 = i0, s1 = i1, s2 = i2, s3 = i3;
        ushort4 g0 = *(const ushort4*)&hb[(size_t)s0 * HC + lane * 4];
        ushort4 g1 = *(const ushort4*)&hb[(size_t)s1 * HC + lane * 4];
        ushort4 g2 = *(const ushort4*)&hb[(size_t)s2 * HC + lane * 4];
        ushort4 g3 = *(const ushort4*)&hb[(size_t)s3 * HC + lane * 4];
        float w0 = csr_w[(size_t)(p + 0) * 4 + head];
        float w1 = csr_w[(size_t)(p + 1) * 4 + head];
        float w2 = csr_w[(size_t)(p + 2) * 4 + head];
        float w3 = csr_w[(size_t)(p + 3) * 4 + head];
        int nn = p + 4;
        if (nn + 4 <= p1) { i0 = csr_s[nn]; i1 = csr_s[nn + 1]; i2 = csr_s[nn + 2]; i3 = csr_s[nn + 3]; }
        acc.x += us2f(g0.x) * w0 + us2f(g1.x) * w1 + us2f(g2.x) * w2 + us2f(g3.x) * w3;
        acc.y += us2f(g0.y) * w0 + us2f(g1.y) * w1 + us2f(g2.y) * w2 + us2f(g3.y) * w3;
        acc.z += us2f(g0.z) * w0 + us2f(g1.z) * w1 + us2f(g2.z) * w2 + us2f(g3.z) * w3;
        acc.w += us2f(g0.w) * w0 + us2f(g1.w) * w1 + us2f(g2.w) * w2 + us2f(g3.w) * w3;
        ssum += (w0 + w1) + (w2 + w3);
    }
    for (; p < p1; p++) {
        int s = csr_s[p];
        float wv = csr_w[(size_t)p * 4 + head];
        ushort4 hs = *(const ushort4*)&hb[(size_t)s * HC + lane * 4];
        acc.x += us2f(hs.x) * wv;
        acc.y += us2f(hs.y) * wv;
        acc.z += us2f(hs.z) * wv;
        acc.w += us2f(hs.w) * wv;
        ssum += wv;
    }
    float inv = 1.f / ssum;
    ushort4 o;
    o.x = f2us(lrelu_act(acc.x * inv + ldin(bias, isbf, lane * 4 + 0)));
    o.y = f2us(lrelu_act(acc.y * inv + ldin(bias, isbf, lane * 4 + 1)));
    o.z = f2us(lrelu_act(acc.z * inv + ldin(bias, isbf, lane * 4 + 2)));
    o.w = f2us(lrelu_act(acc.w * inv + ldin(bias, isbf, lane * 4 + 3)));
    *(ushort4*)&outn[(size_t)n * HC + lane * 4] = o;
}

// ---------------- pooling: (graph, quarter) grid ----------------
__global__ __launch_bounds__(256) void k_pool2(const unsigned short* __restrict__ outn,
                                               const int* __restrict__ gs,
                                               float* __restrict__ sums) {
    int g = blockIdx.x, qq = blockIdx.y, t = threadIdx.x;
    int s = gs[g], e2 = gs[g + 1];
    int len = e2 - s;
    int r0 = s + (len * qq) / 4;
    int r1 = s + (len * (qq + 1)) / 4;
    float a0 = 0.f, a1 = 0.f, a2 = 0.f, a3 = 0.f;
    int r = r0;
    for (; r + 4 <= r1; r += 4) {
        a0 += us2f(outn[(size_t)(r + 0) * HC + t]);
        a1 += us2f(outn[(size_t)(r + 1) * HC + t]);
        a2 += us2f(outn[(size_t)(r + 2) * HC + t]);
        a3 += us2f(outn[(size_t)(r + 3) * HC + t]);
    }
    for (; r < r1; r++) a0 += us2f(outn[(size_t)r * HC + t]);
    float v = (a0 + a1) + (a2 + a3);
    if (r1 > r0) atomicAdd(&sums[(size_t)g * HC + t], v);
}

// ---------------- final FC (mean-divide folded in, dual-dtype out) ----------------
__global__ __launch_bounds__(256) void k_fc(const float* __restrict__ sums,
                                            const int* __restrict__ gs,
                                            const void* __restrict__ fw,
                                            const void* __restrict__ fb,
                                            void* __restrict__ out,
                                            const int* __restrict__ flag) {
    __shared__ float pl[HC];
    int isbf = *flag;
    int g = blockIdx.y;
    int o = blockIdx.x * 256 + threadIdx.x;
    int c = gs[g + 1] - gs[g];
    float inv = 1.f / (float)(c > 1 ? c : 1);
    pl[threadIdx.x] = sums[(size_t)g * HC + threadIdx.x] * inv;
    __syncthreads();
    float acc = ldin(fb, isbf, o);
#pragma unroll 8
    for (int k = 0; k < HC; k++) acc += pl[k] * ldin(fw, isbf, (size_t)k * NOUT + o);
    size_t oi = (size_t)g * NOUT + o;
    if (isbf) ((bf16*)out)[oi] = __float2bfloat16(acc);
    else      ((float*)out)[oi] = acc;
}

extern "C" void kernel_launch(void* const* d_in, const int* in_sizes, int n_in,
                              void* d_out, int out_size, void* d_ws, size_t ws_size,
                              hipStream_t stream) {
    const void* x     = d_in[0];
    const int*  ei    = (const int*)d_in[1];
    const int*  batch = (const int*)d_in[2];
    const void* lin_w = d_in[3];
    const void* att_s = d_in[4];
    const void* att_d = d_in[5];
    const void* bias  = d_in[6];
    const void* fc1w  = d_in[7];
    const void* fc1b  = d_in[8];

    char* p = (char*)d_ws;
    unsigned short* hb   = (unsigned short*)p; p += (size_t)N * HC * 2;   // 25.6 MB
    unsigned short* outn = (unsigned short*)p; p += (size_t)N * HC * 2;   // 25.6 MB
    float* a_src  = (float*)p; p += (size_t)N * H * 4;
    float* a_dst  = (float*)p; p += (size_t)N * H * 4;
    int* cnt      = (int*)p;   p += (size_t)N * 4;                        // cnt+sums zeroed together
    float* sums   = (float*)p; p += (size_t)G * HC * 4;
    int* off      = (int*)p;   p += (size_t)(N + 4) * 4;
    int* cur      = (int*)p;   p += (size_t)N * 4;
    int* csr_s    = (int*)p;   p += (size_t)E * 4;                        // 3.2 MB
    float* csr_w  = (float*)p; p += (size_t)E * H * 4;                    // 12.8 MB
    unsigned short* bswz = (unsigned short*)p; p += (size_t)160 * 64 * 8 * 2;
    int* bsum     = (int*)p;   p += 1024;
    int* gs       = (int*)p;   p += (size_t)(G + 4) * 4;
    int* flag     = (int*)p;   p += 16;

    const int NB = (N + 255) / 256;  // 196

    k_pre<<<NZB + 40 + 1, 256, 0, stream>>>((const unsigned short*)x, lin_w, batch,
                                            flag, cnt, bswz, gs);
    k_lin2<<<512, 256, 0, stream>>>(x, bswz, att_s, att_d, hb, a_src, a_dst, flag);
    k_hist<<<(E + 255) / 256, 256, 0, stream>>>(ei + E, cnt);
    k_scan1<<<NB, 256, 0, stream>>>(cnt, bsum);
    k_scan23<<<NB, 256, 0, stream>>>(bsum, NB, cnt, off, cur);
    k_scatter<<<(E + 255) / 256, 256, 0, stream>>>(ei, a_src, a_dst, cur, csr_s, csr_w);
    k_agg<<<(N + 3) / 4, 256, 0, stream>>>(hb, a_src, a_dst, off, csr_s, csr_w, bias, outn, flag);
    k_pool2<<<dim3(G, 4), 256, 0, stream>>>(outn, gs, sums);
    k_fc<<<dim3(NOUT / 256, G), 256, 0, stream>>>(sums, gs, fc1w, fc1b, d_out, flag);
}